// Round 1
// baseline (13495.753 us; speedup 1.0000x reference)
//
#include <hip/hip_runtime.h>
#include <hip/hip_fp16.h>
#include <math.h>

// Persistent RK45 (Dormand-Prince, FSAL) integrator for
//   dy/dt = y * (r + A@y + eps@P[d(t)]),  n=4096, up to 512 adaptive steps.
// R8: single-phase tagged exchange. R7's two-phase barrier had 3 serialized
// global round-trips per stage (k+flag publish -> block0 flag scan -> bword
// broadcast -> k pull); counters showed VALUBusy 9.8% => ~90% of the 4.3us
// stage is that latency chain. Now each k is published as ONE atomic 8-byte
// word (gen<<32 | float bits): tag and payload land atomically together, so
// consumers poll their 16 tagged words directly -- no flags, no block0 hop,
// no separate pull. One store-visibility + one load round-trip per stage.
//   WAR safety: gen-parity double buffer; block b publishes gen g+2 only
//   after consuming all of g+1, which requires every block published g+1,
//   which requires every block finished consuming g. tag==gen is exact.
//   err (stage 7): every block polls all 256 tagged partials and reduces in
//   R7's exact order (err[lane+j*64], j=0..3, shfl_xor tree) -> bitwise-
//   identical es in all blocks -> identical accept decisions/trajectory.
// Congestion (R5 lesson): first sweep is a one-shot 16-load burst/thread;
// retries reload only pending words with s_sleep backoff (a late block
// leaves ~16 pending words per consumer block, not 4096).
// A stays permanently in registers as fp16 (zero steady-state HBM traffic).

#define N        4096
#define NBLK     256
#define NTHR     256
#define ROWS     16          // rows of A per block (NBLK*ROWS == N)
#define MAXSTEP  512
#define PERTS    8
#define KW       16          // tagged k-words per thread (N/NTHR)

typedef unsigned long long ull;

static_assert(NBLK * ROWS == N, "row partition");
static_assert(NTHR * 16 == N, "column partition (4 float4 per thread)");
static_assert(NTHR * KW == N, "tagged-word partition");

__device__ __forceinline__ float4 ld4(const float* p){ return *reinterpret_cast<const float4*>(p); }
__device__ __forceinline__ void   st4(float* p, float4 v){ *reinterpret_cast<float4*>(p) = v; }

__global__ void __launch_bounds__(NTHR, 1)
mbpert_rk45_kernel(const float* __restrict__ x, const int* __restrict__ tptr,
                   const float* __restrict__ r, const float* __restrict__ A,
                   const float* __restrict__ eps, const float* __restrict__ Pm,
                   float* __restrict__ out, ull* __restrict__ W, int Tm)
{
  __shared__ float khist[6][N];        // 96 KB k-history (gfx950: 160KB LDS/WG)
  __shared__ float part_sm[ROWS * 4];  // per-wave matvec partials
  __shared__ float ys_rows[ROWS];      // stage vector at our 16 row indices
  __shared__ float ysb_rows[ROWS];     // base vector at our 16 row indices
  __shared__ float r_sh[ROWS];
  __shared__ float eps_sh[ROWS * PERTS];
  __shared__ float P_sh[32 * PERTS];
  __shared__ float epr_sh[ROWS];
  __shared__ float es_sh;

  const int tid = threadIdx.x;
  const int b   = blockIdx.x;
  const int rowbase = b * ROWS;
  const int lane = tid & 63;
  const int wv   = tid >> 6;

  ull* errb = W;               // [NBLK] tagged err partials (gen<<32 | bits)
  ull* kx0  = W + NBLK;        // [N]    tagged k, even gens
  ull* kx1  = W + NBLK + N;    // [N]    tagged k, odd gens

  // ---- persistent LDS constants ----
  if (tid < ROWS)             r_sh[tid]   = r[rowbase + tid];
  if (tid < ROWS * PERTS)     eps_sh[tid] = eps[rowbase * PERTS + tid];
  if (tid < (Tm + 1) * PERTS) P_sh[tid]   = Pm[tid];
  if (tid < ROWS)             ysb_rows[tid] = x[rowbase + tid];

  // ---- A fragment -> registers (fp16), once ----
  // Thread owns cols (q*256+tid)*4..+3 (q=0..3) of rows rowbase..rowbase+15.
  __half2 Af[ROWS][8];
  #pragma unroll
  for (int rr = 0; rr < ROWS; rr++){
    const float* Ar = A + (size_t)(rowbase + rr) * N;
    #pragma unroll
    for (int q = 0; q < 4; q++){
      int c = (q * NTHR + tid) * 4;
      float4 a = ld4(Ar + c);
      Af[rr][2*q]   = __floats2half2_rn(a.x, a.y);
      Af[rr][2*q+1] = __floats2half2_rn(a.z, a.w);
    }
  }

  float4 ysbf[4], ysf[4];              // base / stage vector fragments (fp32)
  #pragma unroll
  for (int q = 0; q < 4; q++) ysbf[q] = ld4(x + (q * NTHR + tid) * 4);
  __syncthreads();

  const float t_end = (float)(*tptr);
  const float Tf    = (float)Tm;
  float t = 0.0f;
  float h = t_end * 0.01f;
  unsigned gen = 0;

  // matvec from registers: acc over our 16 cols, wave-reduce, park in part_sm
  auto mv = [&](){
    float acc[ROWS];
    #pragma unroll
    for (int rr = 0; rr < ROWS; rr++) acc[rr] = 0.0f;
    #pragma unroll
    for (int q = 0; q < 4; q++){
      float4 y = ysf[q];
      #pragma unroll
      for (int rr = 0; rr < ROWS; rr++){
        float2 lo = __half22float2(Af[rr][2*q]);
        float2 hi = __half22float2(Af[rr][2*q+1]);
        acc[rr] = fmaf(lo.x, y.x, fmaf(lo.y, y.y, fmaf(hi.x, y.z, fmaf(hi.y, y.w, acc[rr]))));
      }
    }
    __syncthreads();                   // part_sm free from previous stage
    #pragma unroll
    for (int rr = 0; rr < ROWS; rr++){
      float s = acc[rr];
      #pragma unroll
      for (int off = 32; off; off >>= 1) s += __shfl_xor(s, off, 64);
      if (lane == 0) part_sm[rr * 4 + wv] = s;
    }
    __syncthreads();
  };

  // k for row `tid` (tid<ROWS): y_s * (r + A@y_s + eps@P[d])
  auto kval = [&](float ts) -> float {
    int d = (int)((Tf * ts) / 30.0f);
    d = d < 0 ? 0 : (d > Tm ? Tm : d);
    float dot = part_sm[tid*4] + part_sm[tid*4+1] + part_sm[tid*4+2] + part_sm[tid*4+3];
    float ep = 0.f;
    #pragma unroll
    for (int p = 0; p < PERTS; p++) ep += eps_sh[tid * PERTS + p] * P_sh[d * PERTS + p];
    return ys_rows[tid] * (r_sh[tid] + dot + ep);
  };

  // ys = ysb + h * sum(cf[m] * khist[sli[m]]) over our 16 columns
  auto build = [&](const int* sli, const float* cf, int nk){
    #pragma unroll
    for (int q = 0; q < 4; q++){
      int c = (q * NTHR + tid) * 4;
      float4 v = ysbf[q];
      for (int m = 0; m < nk; m++){
        float cc = h * cf[m];
        float4 kv = ld4(&khist[sli[m]][c]);
        v.x = fmaf(cc, kv.x, v.x); v.y = fmaf(cc, kv.y, v.y);
        v.z = fmaf(cc, kv.z, v.z); v.w = fmaf(cc, kv.w, v.w);
      }
      ysf[q] = v;
      int o = c - rowbase;             // c,rowbase multiples of 4/16: full containment
      if (o >= 0 && o < ROWS) st4(&ys_rows[o], v);
    }
    __syncthreads();
  };

  // single-phase tagged exchange: publish 16 tagged k's, poll all N tagged
  // words directly (16/thread, stride-256 coalesced), land them in khist[slot]
  auto exchange = [&](int slot, float kv, bool werr, float errv){
    ++gen;
    ull* kx = (gen & 1u) ? kx1 : kx0;            // double buffer by parity
    const ull tag = ((ull)gen) << 32;
    if (tid < ROWS){
      __hip_atomic_store(&kx[rowbase + tid], tag | (ull)__float_as_uint(kv),
                         __ATOMIC_RELAXED, __HIP_MEMORY_SCOPE_AGENT);
    }
    if (werr && tid == 0){
      __hip_atomic_store(&errb[b], tag | (ull)__float_as_uint(errv),
                         __ATOMIC_RELAXED, __HIP_MEMORY_SCOPE_AGENT);
    }

    // ---- consume: one-shot burst, then retry only pending words ----
    ull got[KW];
    #pragma unroll
    for (int w = 0; w < KW; w++)
      got[w] = __hip_atomic_load(&kx[w * NTHR + tid],
                                 __ATOMIC_RELAXED, __HIP_MEMORY_SCOPE_AGENT);
    unsigned pend = 0;
    #pragma unroll
    for (int w = 0; w < KW; w++)
      if ((unsigned)(got[w] >> 32) != gen) pend |= (1u << w);
    while (pend){
      __builtin_amdgcn_s_sleep(1);
      #pragma unroll
      for (int w = 0; w < KW; w++){
        if (pend & (1u << w)){
          ull g = __hip_atomic_load(&kx[w * NTHR + tid],
                                    __ATOMIC_RELAXED, __HIP_MEMORY_SCOPE_AGENT);
          if ((unsigned)(g >> 32) == gen){ got[w] = g; pend &= ~(1u << w); }
        }
      }
    }
    #pragma unroll
    for (int w = 0; w < KW; w++)
      khist[slot][w * NTHR + tid] = __uint_as_float((unsigned)got[w]);

    if (werr && wv == 0){
      // every block polls + reduces the 256 tagged err partials in R7's exact
      // order -> bitwise-identical es in all blocks -> identical accept path
      ull ge[4];
      #pragma unroll
      for (int j = 0; j < 4; j++)
        ge[j] = __hip_atomic_load(&errb[lane + j * 64],
                                  __ATOMIC_RELAXED, __HIP_MEMORY_SCOPE_AGENT);
      unsigned ep = 0;
      #pragma unroll
      for (int j = 0; j < 4; j++)
        if ((unsigned)(ge[j] >> 32) != gen) ep |= (1u << j);
      while (ep){
        __builtin_amdgcn_s_sleep(1);
        #pragma unroll
        for (int j = 0; j < 4; j++){
          if (ep & (1u << j)){
            ull g = __hip_atomic_load(&errb[lane + j * 64],
                                      __ATOMIC_RELAXED, __HIP_MEMORY_SCOPE_AGENT);
            if ((unsigned)(g >> 32) == gen){ ge[j] = g; ep &= ~(1u << j); }
          }
        }
      }
      float es = 0.f;
      #pragma unroll
      for (int j = 0; j < 4; j++) es += __uint_as_float((unsigned)ge[j]);
      #pragma unroll
      for (int off = 32; off; off >>= 1) es += __shfl_xor(es, off, 64);
      if (lane == 0) es_sh = es;
    }
    __syncthreads();                             // khist[slot]/es_sh ready
  };

  int sl[6] = {0, 1, 2, 3, 4, 5};      // logical k1..k6 -> physical LDS slots
  bool exhausted = true;

  for (int n = 0; n < MAXSTEP; ++n){
    if (n > 0){
      float es = es_sh;                          // set by last stage-7 exchange
      float enorm = sqrtf(es * (1.0f / (float)N));
      bool accept = (enorm <= 1.0f);
      if (accept){
        t += h;
        int tmp = sl[0]; sl[0] = sl[1]; sl[1] = tmp;  // FSAL: k1 <- k7 (in k2's slot)
        #pragma unroll
        for (int q = 0; q < 4; q++) ysbf[q] = ysf[q];
        if (tid < ROWS) ysb_rows[tid] = ys_rows[tid];
      }
      float fac = 0.9f * powf(enorm + 1e-10f, -0.2f);
      fac = fminf(fmaxf(fac, 0.2f), 10.0f);
      h *= fac;
      __syncthreads();
    }
    if (t >= t_end) { exhausted = false; break; }
    h = fminf(h, t_end - t);
    if (!(h > 0.0f)) { exhausted = false; break; }

    if (n == 0){
      // ---- stage 1 (once ever; FSAL covers later steps) ----
      #pragma unroll
      for (int q = 0; q < 4; q++){
        ysf[q] = ysbf[q];
        int c = (q * NTHR + tid) * 4, o = c - rowbase;
        if (o >= 0 && o < ROWS) st4(&ys_rows[o], ysf[q]);
      }
      __syncthreads();
      mv();
      float kv = (tid < ROWS) ? kval(t) : 0.f;
      exchange(sl[0], kv, false, 0.f);
    }

    // ---- stage 2 ----
    { const float cf[1] = {0.2f}; const int s_[1] = {sl[0]};
      build(s_, cf, 1); mv();
      float kv = (tid < ROWS) ? kval(t + 0.2f * h) : 0.f;
      exchange(sl[1], kv, false, 0.f); }

    // ---- stage 3 ----
    { const float cf[2] = {3.f/40.f, 9.f/40.f}; const int s_[2] = {sl[0], sl[1]};
      build(s_, cf, 2); mv();
      float kv = (tid < ROWS) ? kval(t + 0.3f * h) : 0.f;
      exchange(sl[2], kv, false, 0.f); }

    // ---- stage 4 ----
    { const float cf[3] = {44.f/45.f, -56.f/15.f, 32.f/9.f};
      const int s_[3] = {sl[0], sl[1], sl[2]};
      build(s_, cf, 3); mv();
      float kv = (tid < ROWS) ? kval(t + 0.8f * h) : 0.f;
      exchange(sl[3], kv, false, 0.f); }

    // ---- stage 5 ----
    { const float cf[4] = {19372.f/6561.f, -25360.f/2187.f, 64448.f/6561.f, -212.f/729.f};
      const int s_[4] = {sl[0], sl[1], sl[2], sl[3]};
      build(s_, cf, 4); mv();
      float kv = (tid < ROWS) ? kval(t + (8.f/9.f) * h) : 0.f;
      exchange(sl[4], kv, false, 0.f); }

    // ---- stage 6 ----
    { const float cf[5] = {9017.f/3168.f, -355.f/33.f, 46732.f/5247.f, 49.f/176.f, -5103.f/18656.f};
      const int s_[5] = {sl[0], sl[1], sl[2], sl[3], sl[4]};
      build(s_, cf, 5); mv();
      float kv = (tid < ROWS) ? kval(t + h) : 0.f;
      exchange(sl[5], kv, false, 0.f); }

    // ---- stage 7: ys = y5 candidate; err partial; k7 -> sl[1] (k2 dead) ----
    { const float cf[5] = {35.f/384.f, 500.f/1113.f, 125.f/192.f, -2187.f/6784.f, 11.f/84.f};
      const int s_[5] = {sl[0], sl[2], sl[3], sl[4], sl[5]};
      build(s_, cf, 5);                // ys == y5 candidate; ys_rows updated
      mv();
      float k7v = 0.f, errv = 0.f;
      if (tid < ROWS){
        k7v = kval(t + h);
        int gi = rowbase + tid;
        float e = (71.f/57600.f)  * khist[sl[0]][gi] - (71.f/16695.f)    * khist[sl[2]][gi]
                + (71.f/1920.f)   * khist[sl[3]][gi] - (17253.f/339200.f)* khist[sl[4]][gi]
                + (22.f/525.f)    * khist[sl[5]][gi] - (1.f/40.f)        * k7v;
        e *= h;
        float sc = 1e-6f + 1e-3f * fmaxf(fabsf(ysb_rows[tid]), fabsf(ys_rows[tid]));
        float q = e / sc;
        epr_sh[tid] = q * q;
      }
      __syncthreads();
      if (tid == 0){
        float s = 0.f;
        #pragma unroll
        for (int i = 0; i < ROWS; i++) s += epr_sh[i];
        errv = s;
      }
      exchange(sl[1], k7v, true, errv);          // tagged k7 + tagged err
    }
  }

  if (exhausted){
    // apply the final (iteration 511) accept decision, as the reference does
    float es = es_sh;
    bool accept = sqrtf(es * (1.0f / (float)N)) <= 1.0f;
    if (tid < ROWS) out[rowbase + tid] = accept ? ys_rows[tid] : ysb_rows[tid];
  } else {
    if (tid < ROWS) out[rowbase + tid] = ysb_rows[tid];
  }
}

extern "C" void kernel_launch(void* const* d_in, const int* in_sizes, int n_in,
                              void* d_out, int out_size, void* d_ws, size_t ws_size,
                              hipStream_t stream)
{
  const float* x   = (const float*)d_in[0];
  const int*   tp  = (const int*)  d_in[1];
  const float* r   = (const float*)d_in[2];
  const float* A   = (const float*)d_in[3];
  const float* eps = (const float*)d_in[4];
  const float* Pm  = (const float*)d_in[5];
  float* out = (float*)d_out;
  ull*   W   = (ull*)d_ws;
  int Tm = in_sizes[5] / PERTS - 1;   // P rows - 1  (== 30)

  // zero all gen tags (errb[256] + kx0[N] + kx1[N]); ws re-poisoned per call
  hipMemsetAsync(d_ws, 0, (size_t)(NBLK + 2 * N) * sizeof(ull), stream);
  mbpert_rk45_kernel<<<dim3(NBLK), dim3(NTHR), 0, stream>>>(
      x, tp, r, A, eps, Pm, out, W, Tm);
}